// Round 12
// baseline (243.103 us; speedup 1.0000x reference)
//
#include <hip/hip_runtime.h>
#include <stdint.h>

// SelfOrganizingBrain: B=1024, IN=784, E=256, NCLS=10, N=64 blocks, NJUMPS=4.
// R11: L2-BW attack. R10 showed dispatch count is irrelevant -> kernels are
// L2-bound on redundant weight streams (~1.15 GB total @ ~5.5 TB/s ~= 210us,
// matches 227us + VALUBusy 12%). R11 halves traffic: CH=8 rows/chunk in all
// B kernels (chunks ~300->~135), embed = 8 rows x 128 cols/WG (grid 256,
// Wemb 205->102 MB), A0 split to its own kernel. acc[8][2] register tile,
// 2-stage weight pipeline. 7 dispatches: E -> A0 -> 4x(B+A) -> B4+head.

#define BATCH 1024
#define EDIM  256
#define INDIM 784
#define CH    8
#define GRID_B 192   // max chunks = 64 + (1024-64)/8 = 184 <= 192 (8*24)

// ---------------- threefry2x32 (exact JAX semantics, validated R0-R10) ----------------
__host__ __device__ inline uint32_t rotl32(uint32_t x, uint32_t d) {
  return (x << d) | (x >> (32u - d));
}
__host__ __device__ inline void threefry2x32(uint32_t k0, uint32_t k1,
                                             uint32_t x0, uint32_t x1,
                                             uint32_t* o0, uint32_t* o1) {
  uint32_t ks2 = k0 ^ k1 ^ 0x1BD11BDAu;
  x0 += k0; x1 += k1;
#define TF_R(a) { x0 += x1; x1 = rotl32(x1, a); x1 ^= x0; }
  TF_R(13) TF_R(15) TF_R(26) TF_R(6)   x0 += k1;  x1 += ks2 + 1u;
  TF_R(17) TF_R(29) TF_R(16) TF_R(24)  x0 += ks2; x1 += k0  + 2u;
  TF_R(13) TF_R(15) TF_R(26) TF_R(6)   x0 += k0;  x1 += k1  + 3u;
  TF_R(17) TF_R(29) TF_R(16) TF_R(24)  x0 += k1;  x1 += ks2 + 4u;
  TF_R(13) TF_R(15) TF_R(26) TF_R(6)   x0 += ks2; x1 += k0  + 5u;
#undef TF_R
  *o0 = x0; *o1 = x1;
}
__device__ inline uint32_t jax_bits12288(uint32_t k0, uint32_t k1, uint32_t L) {
  uint32_t o0, o1;
  if (L < 6144u) { threefry2x32(k0, k1, L, L + 6144u, &o0, &o1); return o0; }
  else           { threefry2x32(k0, k1, L - 6144u, L, &o0, &o1); return o1; }
}
__device__ inline float jax_uniform(uint32_t bits) {
  const float minv = 1e-6f;
  const float maxv = (float)(1.0 - 1e-06);
  const float span = maxv - minv;
  uint32_t fb = (bits >> 9) | 0x3f800000u;
  float f = __uint_as_float(fb) - 1.0f;
  float u = __fadd_rn(__fmul_rn(f, span), minv);
  return fmaxf(minv, u);
}
__device__ inline float gumbel_val(int s, int b, int c) {
  uint32_t fk0, fk1;
  threefry2x32(0u, 42u, 0u, (uint32_t)s, &fk0, &fk1);   // fold_in(key(42), s)
  const uint32_t L = (uint32_t)(b * 12 + c);
  const float u = jax_uniform(jax_bits12288(fk0, fk1, L));
  return -logf(-logf(u));
}
__device__ inline int addr_argmax(const float* v) {
  int i0 = 0, i1 = 0, i2 = 0;
  { float b = v[0];
    for (int c = 1; c < 4; c++) { float x = v[c];     if (x > b) { b = x; i0 = c; } } }
  { float b = v[4];
    for (int c = 1; c < 4; c++) { float x = v[4 + c]; if (x > b) { b = x; i1 = c; } } }
  { float b = v[8];
    for (int c = 1; c < 4; c++) { float x = v[8 + c]; if (x > b) { b = x; i2 = c; } } }
  return i0 * 16 + i1 * 4 + i2;
}

// ---- 8 coalesced weight loads (4 k x 2 cols at stride CSTR) ----
#define LDW8(dst, Wc, kkq, CSTR)                                                \
  { _Pragma("unroll")                                                           \
    for (int _q = 0; _q < 4; _q++) {                                            \
      _Pragma("unroll")                                                         \
      for (int _cc = 0; _cc < 2; _cc++)                                         \
        dst[_q * 2 + _cc] = (Wc)[(size_t)((kkq) + _q) * EDIM + _cc * (CSTR)];   \
    } }

// one row's 8 FMA (4 k x 2 cols); k ascending per accumulator
#define FMA_ROW(acc, ri, rv, wv)                                                \
  acc[ri][0] = fmaf(rv.x, wv[0], acc[ri][0]);                                   \
  acc[ri][0] = fmaf(rv.y, wv[2], acc[ri][0]);                                   \
  acc[ri][0] = fmaf(rv.z, wv[4], acc[ri][0]);                                   \
  acc[ri][0] = fmaf(rv.w, wv[6], acc[ri][0]);                                   \
  acc[ri][1] = fmaf(rv.x, wv[1], acc[ri][1]);                                   \
  acc[ri][1] = fmaf(rv.y, wv[3], acc[ri][1]);                                   \
  acc[ri][1] = fmaf(rv.z, wv[5], acc[ri][1]);                                   \
  acc[ri][1] = fmaf(rv.w, wv[7], acc[ri][1]);

// 64 FMA from one 8-weight batch; 8 LDS b128 row broadcasts
#define FMA32(acc, wv, XSarr, SROW, kabs)                                       \
  { const float4 _r0 = *(const float4*)&(XSarr)[0 * (SROW) + (kabs)];           \
    const float4 _r1 = *(const float4*)&(XSarr)[1 * (SROW) + (kabs)];           \
    const float4 _r2 = *(const float4*)&(XSarr)[2 * (SROW) + (kabs)];           \
    const float4 _r3 = *(const float4*)&(XSarr)[3 * (SROW) + (kabs)];           \
    const float4 _r4 = *(const float4*)&(XSarr)[4 * (SROW) + (kabs)];           \
    const float4 _r5 = *(const float4*)&(XSarr)[5 * (SROW) + (kabs)];           \
    const float4 _r6 = *(const float4*)&(XSarr)[6 * (SROW) + (kabs)];           \
    const float4 _r7 = *(const float4*)&(XSarr)[7 * (SROW) + (kabs)];           \
    FMA_ROW(acc, 0, _r0, wv) FMA_ROW(acc, 1, _r1, wv)                           \
    FMA_ROW(acc, 2, _r2, wv) FMA_ROW(acc, 3, _r3, wv)                           \
    FMA_ROW(acc, 4, _r4, wv) FMA_ROW(acc, 5, _r5, wv)                           \
    FMA_ROW(acc, 6, _r6, wv) FMA_ROW(acc, 7, _r7, wv) }

// register-tiled GEMM slice (8 rows x 2 cols), 2-stage pipeline, KS mult of 8
#define GEMM_TILE8(Wbase, COLB, CSTR, XSarr, SROW, kb, KS, acc)                 \
  { const float* _Wc = (Wbase) + (size_t)(kb) * EDIM + (COLB);                  \
    float _wvA[8], _wvB[8];                                                     \
    LDW8(_wvA, _Wc, 0, CSTR)                                                    \
    _Pragma("unroll 1")                                                         \
    for (int _kk = 0; _kk < (KS); _kk += 8) {                                   \
      LDW8(_wvB, _Wc, _kk + 4, CSTR)                                            \
      FMA32(acc, _wvA, XSarr, SROW, (kb) + _kk)                                 \
      if (_kk + 8 < (KS)) LDW8(_wvA, _Wc, _kk + 8, CSTR)                        \
      FMA32(acc, _wvB, XSarr, SROW, (kb) + _kk + 4)                             \
    } }

// layer-2 variant: activations from H[k][0..7] (two b128 per k)
#define FMA32H(acc, wv, Harr, kabs)                                             \
  { _Pragma("unroll")                                                           \
    for (int _q = 0; _q < 4; _q++) {                                            \
      const float4 _hl = *(const float4*)&(Harr)[((kabs) + _q) * 8];            \
      const float4 _hh = *(const float4*)&(Harr)[((kabs) + _q) * 8 + 4];        \
      _Pragma("unroll")                                                         \
      for (int _cc = 0; _cc < 2; _cc++) {                                       \
        acc[0][_cc] = fmaf(_hl.x, wv[_q * 2 + _cc], acc[0][_cc]);               \
        acc[1][_cc] = fmaf(_hl.y, wv[_q * 2 + _cc], acc[1][_cc]);               \
        acc[2][_cc] = fmaf(_hl.z, wv[_q * 2 + _cc], acc[2][_cc]);               \
        acc[3][_cc] = fmaf(_hl.w, wv[_q * 2 + _cc], acc[3][_cc]);               \
        acc[4][_cc] = fmaf(_hh.x, wv[_q * 2 + _cc], acc[4][_cc]);               \
        acc[5][_cc] = fmaf(_hh.y, wv[_q * 2 + _cc], acc[5][_cc]);               \
        acc[6][_cc] = fmaf(_hh.z, wv[_q * 2 + _cc], acc[6][_cc]);               \
        acc[7][_cc] = fmaf(_hh.w, wv[_q * 2 + _cc], acc[7][_cc]);               \
      } } }

#define GEMM_TILE_H8(Wbase, COLB, CSTR, Harr, kb, KS, acc)                      \
  { const float* _Wc = (Wbase) + (size_t)(kb) * EDIM + (COLB);                  \
    float _wvA[8], _wvB[8];                                                     \
    LDW8(_wvA, _Wc, 0, CSTR)                                                    \
    _Pragma("unroll 1")                                                         \
    for (int _kk = 0; _kk < (KS); _kk += 8) {                                   \
      LDW8(_wvB, _Wc, _kk + 4, CSTR)                                            \
      FMA32H(acc, _wvA, Harr, (kb) + _kk)                                       \
      if (_kk + 8 < (KS)) LDW8(_wvA, _Wc, _kk + 8, CSTR)                        \
      FMA32H(acc, _wvB, Harr, (kb) + _kk + 4)                                   \
    } }

// write acc -> P[kg][col][8] (NCOL cols per kg)
#define P_STORE8(P, kg, NCOL, LCOL, CSTR, acc)                                  \
  { _Pragma("unroll")                                                           \
    for (int _cc = 0; _cc < 2; _cc++) {                                         \
      const int _col = (LCOL) + _cc * (CSTR);                                   \
      *(float4*)&(P)[(((kg) * (NCOL)) + _col) * 8] =                            \
        make_float4(acc[0][_cc], acc[1][_cc], acc[2][_cc], acc[3][_cc]);        \
      *(float4*)&(P)[(((kg) * (NCOL)) + _col) * 8 + 4] =                        \
        make_float4(acc[4][_cc], acc[5][_cc], acc[6][_cc], acc[7][_cc]);        \
    } }

// reduce NPART partials + bias -> lo4 (rows 0-3), hi4 (rows 4-7)
#define P_REDUCE(P, col, NCOL, NPART, bias, lo4, hi4)                           \
  { lo4 = *(const float4*)&(P)[(col) * 8];                                      \
    hi4 = *(const float4*)&(P)[(col) * 8 + 4];                                  \
    _Pragma("unroll")                                                           \
    for (int _pw = 1; _pw < (NPART); _pw++) {                                   \
      const float4 _pl = *(const float4*)&(P)[((_pw * (NCOL)) + (col)) * 8];    \
      const float4 _ph = *(const float4*)&(P)[((_pw * (NCOL)) + (col)) * 8 + 4];\
      lo4.x += _pl.x; lo4.y += _pl.y; lo4.z += _pl.z; lo4.w += _pl.w;           \
      hi4.x += _ph.x; hi4.y += _ph.y; hi4.z += _ph.z; hi4.w += _ph.w;           \
    }                                                                           \
    lo4.x += (bias); lo4.y += (bias); lo4.z += (bias); lo4.w += (bias);         \
    hi4.x += (bias); hi4.y += (bias); hi4.z += (bias); hi4.w += (bias); }

// ---- addr tail (512 thr, 8 rows): H reduce, logits (32 slices of 8), gumbel ----
#define ADDR_TAIL8(P, H, P2a, vals, ab1, aW2, ab2, astep, ROWEXPR)              \
  { if (t < 256) {                                                              \
      float4 lo, hi; P_REDUCE(P, t, 256, 4, (ab1)[t], lo, hi);                  \
      *(float4*)&(H)[t * 8] = make_float4(fmaxf(lo.x, 0.f), fmaxf(lo.y, 0.f),   \
                                          fmaxf(lo.z, 0.f), fmaxf(lo.w, 0.f));  \
      *(float4*)&(H)[t * 8 + 4] = make_float4(fmaxf(hi.x, 0.f), fmaxf(hi.y, 0.f),\
                                              fmaxf(hi.z, 0.f), fmaxf(hi.w, 0.f));\
    }                                                                           \
    __syncthreads();                                                            \
    { const int c = t & 15, ksl = t >> 4;                                       \
      float a2[8] = {0.f,0.f,0.f,0.f,0.f,0.f,0.f,0.f};                          \
      if (c < 12) {                                                             \
        const int k0 = ksl * 8;                                                 \
        _Pragma("unroll")                                                       \
        for (int k = k0; k < k0 + 8; k++) {                                     \
          const float4 hl = *(const float4*)&(H)[k * 8];                        \
          const float4 hh = *(const float4*)&(H)[k * 8 + 4];                    \
          const float w = (aW2)[k * 12 + c];                                    \
          a2[0] = fmaf(hl.x, w, a2[0]); a2[1] = fmaf(hl.y, w, a2[1]);           \
          a2[2] = fmaf(hl.z, w, a2[2]); a2[3] = fmaf(hl.w, w, a2[3]);           \
          a2[4] = fmaf(hh.x, w, a2[4]); a2[5] = fmaf(hh.y, w, a2[5]);           \
          a2[6] = fmaf(hh.z, w, a2[6]); a2[7] = fmaf(hh.w, w, a2[7]);           \
        }                                                                       \
      }                                                                         \
      *(float4*)&(P2a)[(ksl * 16 + c) * 8] = make_float4(a2[0], a2[1], a2[2], a2[3]); \
      *(float4*)&(P2a)[(ksl * 16 + c) * 8 + 4] = make_float4(a2[4], a2[5], a2[6], a2[7]); \
    }                                                                           \
    __syncthreads();                                                            \
    if (t < 96) {                                                               \
      const int i = t / 12, c = t % 12;                                         \
      float s = 0.f;                                                            \
      _Pragma("unroll")                                                         \
      for (int w = 0; w < 32; w++) s += (P2a)[(w * 16 + c) * 8 + i];            \
      (vals)[i * 12 + c] = s + (ab2)[c] + gumbel_val((astep), (ROWEXPR), c);    \
    }                                                                           \
    __syncthreads();                                                            \
  }

// ============ E: embed 8 rows x 128 cols/WG (grid 256, 512 thr) ============
__global__ __launch_bounds__(512, 2) void k_embed(
    const float* __restrict__ x, const float* __restrict__ Wemb,
    const float* __restrict__ bemb,
    float* __restrict__ state, float* __restrict__ initial) {
  __shared__ __align__(16) float XS[8 * INDIM];    // 25 KB
  __shared__ __align__(16) float P[8 * 128 * 8];   // 32 KB
  const int t = threadIdx.x;
  const int rg = blockIdx.x >> 1, chh = blockIdx.x & 1;
  const int b0 = rg * 8;
  const int jch = t & 63, kg8 = t >> 6;            // 8 K-slices

  { const float4* src = (const float4*)(x + (size_t)b0 * INDIM);
    for (int p = t; p < (8 * INDIM) / 4; p += 512) ((float4*)XS)[p] = src[p];
  }
  __syncthreads();

  { // K-slices [104,104,96,96,96,96,96,96] (bit-identical to R9 slicing)
    const int kb = (kg8 < 2) ? kg8 * 104 : 208 + (kg8 - 2) * 96;
    const int KS = (kg8 < 2) ? 104 : 96;
    float acc[8][2] = {};
    if (kg8 < 2) { GEMM_TILE8(Wemb, chh * 128 + jch, 64, XS, INDIM, kb, 104, acc); }
    else         { GEMM_TILE8(Wemb, chh * 128 + jch, 64, XS, INDIM, kb, 96, acc); }
    (void)KS;
    P_STORE8(P, kg8, 128, jch, 64, acc);
  }
  __syncthreads();
  if (t < 128) { // reduce 8 partials + bias -> state/initial (8 rows)
    float4 lo, hi; P_REDUCE(P, t, 128, 8, bemb[chh * 128 + t], lo, hi);
    const int gcol = chh * 128 + t;
    float sv[8] = { lo.x, lo.y, lo.z, lo.w, hi.x, hi.y, hi.z, hi.w };
#pragma unroll
    for (int i = 0; i < 8; i++) {
      state[(size_t)(b0 + i) * EDIM + gcol] = sv[i];
      initial[(size_t)(b0 + i) * EDIM + gcol] = sv[i];
    }
  }
}

// ============ A0: addr step 0, 8 rows/WG (grid 128, 512 thr) ============
__global__ __launch_bounds__(512, 2) void k_addr0(
    const float* __restrict__ state,
    const float* __restrict__ aW1, const float* __restrict__ ab1,
    const float* __restrict__ aW2, const float* __restrict__ ab2,
    int* __restrict__ nn_all) {
  __shared__ __align__(16) float XS[8 * EDIM];     // 8 KB
  __shared__ __align__(16) float P[4 * 256 * 8];   // 32 KB
  __shared__ __align__(16) float H[EDIM * 8];      // 8 KB
  __shared__ float vals[8 * 12];
  float* const P2a = P;                            // alias (disjoint phases)
  const int t = threadIdx.x, b0 = blockIdx.x * 8;
  const int jc = t & 127, kg = t >> 7;

  ((float4*)XS)[t] = ((const float4*)(state + (size_t)b0 * EDIM))[t];
  __syncthreads();

  { const int kb = kg * 64;
    float acc[8][2] = {};
    GEMM_TILE8(aW1, jc, 128, XS, EDIM, kb, 64, acc);
    P_STORE8(P, kg, 256, jc, 128, acc);
  }
  __syncthreads();
  ADDR_TAIL8(P, H, P2a, vals, ab1, aW2, ab2, 0, b0 + i);
  if (t < 8) nn_all[b0 + t] = addr_argmax(&vals[t * 12]);   // step 0: no exits
}

// ---- routing prologue for B kernels (512 threads, 8 rows/chunk) ----
#define B_ROUTE(nnval_expr)                                                     \
  if (t < 64) hist[t] = 0;                                                      \
  if (t < 8) rowsl[t] = 0;                                                      \
  __syncthreads();                                                              \
  int myv[2]; bool fl[2];                                                       \
  _Pragma("unroll")                                                             \
  for (int p = 0; p < 2; p++) {                                                 \
    const int rr = p * 512 + t;                                                 \
    myv[p] = (nnval_expr);                                                      \
    if (myv[p] >= 0) atomicAdd(&hist[myv[p]], 1);                               \
  }                                                                             \
  __syncthreads();                                                              \
  if (t < 64) {                                                                 \
    const int cnt = hist[t];                                                    \
    const int nch = (cnt + CH - 1) / CH;                                        \
    int icnt = cnt, inch = nch;                                                 \
    _Pragma("unroll")                                                           \
    for (int d = 1; d < 64; d <<= 1) {                                          \
      int t1 = __shfl_up(icnt, d), t2 = __shfl_up(inch, d);                     \
      if (t >= d) { icnt += t1; inch += t2; }                                   \
    }                                                                           \
    const int ench = inch - nch;                                                \
    if (t == 63) meta[3] = inch;                                                \
    if (c >= ench && c < ench + nch) {                                          \
      meta[0] = t; meta[1] = c - ench;                                          \
      meta[2] = min(CH, cnt - (c - ench) * CH);                                 \
    }                                                                           \
  }                                                                             \
  __syncthreads();                                                              \
  if (c >= meta[3]) return;                                                     \
  const int n = meta[0], local = meta[1], m = meta[2];                          \
  {                                                                             \
    const int wid = t >> 6, lane = t & 63;                                      \
    unsigned long long bals[2];                                                 \
    _Pragma("unroll")                                                           \
    for (int p = 0; p < 2; p++) {                                               \
      fl[p] = (myv[p] == n);                                                    \
      bals[p] = __ballot(fl[p]);                                                \
      if (lane == 0) wcnt2[p * 8 + wid] = __popcll(bals[p]);                    \
    }                                                                           \
    __syncthreads();                                                            \
    if (t == 0) { int s = 0;                                                    \
      for (int e = 0; e < 16; e++) { wbase2[e] = s; s += wcnt2[e]; } }          \
    __syncthreads();                                                            \
    const int r0 = local * CH;                                                  \
    _Pragma("unroll")                                                           \
    for (int p = 0; p < 2; p++) {                                               \
      if (fl[p]) {                                                              \
        const int rank = wbase2[p * 8 + wid] +                                  \
          __popcll(bals[p] & ((1ull << lane) - 1ull));                          \
        if (rank >= r0 && rank < r0 + CH) rowsl[rank - r0] = p * 512 + t;       \
      }                                                                         \
    }                                                                           \
    __syncthreads();                                                            \
  }

// ============ B_j + A_{j+1}: routed blocks CH=8 + fused addr (grid 192) ============
__global__ __launch_bounds__(512, 2) void k_block_mid(
    float* __restrict__ state,
    const float* __restrict__ W1, const float* __restrict__ b1,
    const float* __restrict__ W2, const float* __restrict__ b2,
    const float* __restrict__ aW1, const float* __restrict__ ab1,
    const float* __restrict__ aW2, const float* __restrict__ ab2,
    int* __restrict__ nn_all, int rstep) {
  __shared__ __align__(16) float XS[8 * EDIM];     // 8 KB
  __shared__ __align__(16) float P[4 * 256 * 8];   // 32 KB
  __shared__ __align__(16) float H[EDIM * 8];      // 8 KB
  __shared__ float vals[8 * 12];
  __shared__ int hist[64], meta[4], rowsl[8];
  __shared__ int wcnt2[16], wbase2[16];
  __shared__ float denom[8];
  float* const P2a = P;
  const int t = threadIdx.x;
  const int c = ((blockIdx.x & 7) * 24) + (blockIdx.x >> 3);   // XCD swizzle
  const int jc = t & 127, kg = t >> 7;
  const int* nnj = nn_all + rstep * BATCH;

  B_ROUTE(nnj[rr])

  { // stage 8 rows + norms (wave i <-> row i)
    const int i = t >> 6, q = t & 63;
    const int row = rowsl[min(i, m - 1)] & 1023;
    const float4 v = *(const float4*)(state + (size_t)row * EDIM + q * 4);
    ((float4*)XS)[t] = v;
    float sq = v.x * v.x + v.y * v.y + v.z * v.z + v.w * v.w;
#pragma unroll
    for (int d = 32; d >= 1; d >>= 1) sq += __shfl_xor(sq, d);
    if (q == 0) denom[i] = sqrtf(sq) + 1e-6f;
  }
  __syncthreads();

  const float* W1n = W1 + (size_t)n * EDIM * EDIM;
  const float* W2n = W2 + (size_t)n * EDIM * EDIM;
  const int kb = kg * 64;
  { float acc[8][2] = {};
    GEMM_TILE8(W1n, jc, 128, XS, EDIM, kb, 64, acc);
    P_STORE8(P, kg, 256, jc, 128, acc);
  }
  __syncthreads();
  if (t < 256) { // H reduce
    float4 lo, hi; P_REDUCE(P, t, 256, 4, b1[(size_t)n * EDIM + t], lo, hi);
    *(float4*)&H[t * 8] = make_float4(fmaxf(lo.x, 0.f), fmaxf(lo.y, 0.f),
                                      fmaxf(lo.z, 0.f), fmaxf(lo.w, 0.f));
    *(float4*)&H[t * 8 + 4] = make_float4(fmaxf(hi.x, 0.f), fmaxf(hi.y, 0.f),
                                          fmaxf(hi.z, 0.f), fmaxf(hi.w, 0.f));
  }
  __syncthreads();
  { float acc[8][2] = {};
    GEMM_TILE_H8(W2n, jc, 128, H, kb, 64, acc);
    P_STORE8(P, kg, 256, jc, 128, acc);
  }
  __syncthreads();
  if (t < 256) { // epilogue: relu/denom -> state (in-place) + XS (addr input)
    float4 lo, hi; P_REDUCE(P, t, 256, 4, b2[(size_t)n * EDIM + t], lo, hi);
    float sv[8] = { lo.x, lo.y, lo.z, lo.w, hi.x, hi.y, hi.z, hi.w };
#pragma unroll
    for (int i = 0; i < 8; i++) {
      if (i < m) {
        const int row = rowsl[i] & 1023;
        const float v = fmaxf(sv[i], 0.f) / denom[i];
        state[(size_t)row * EDIM + t] = v;
        XS[i * EDIM + t] = v;
      }
    }
  }
  __syncthreads();

  // ---- fused A_{rstep+1} on the 8 new rows ----
  { float acc[8][2] = {};
    GEMM_TILE8(aW1, jc, 128, XS, EDIM, kb, 64, acc);
    P_STORE8(P, kg, 256, jc, 128, acc);
  }
  __syncthreads();
  ADDR_TAIL8(P, H, P2a, vals, ab1, aW2, ab2, rstep + 1, (rowsl[i] & 1023));
  if (t < m) {       // m <= 8
    const int b = rowsl[t] & 1023;
    const int nn = addr_argmax(&vals[t * 12]);
    const int s = rstep + 1;
    if (s < 4) {
      if (nn == 0) {                     // exits now: freeze rounds s..4
        for (int q = s; q <= 4; q++) nn_all[q * BATCH + b] = -1;
      } else nn_all[s * BATCH + b] = nn;
    } else nn_all[4 * BATCH + b] = nn;
  }
}

// ============ B4 + head (grid 192, 512 thr) ============
__global__ __launch_bounds__(512, 2) void k_block_final(
    const float* __restrict__ state,
    const float* __restrict__ W1, const float* __restrict__ b1,
    const float* __restrict__ W2, const float* __restrict__ b2,
    const float* __restrict__ initial,
    const float* __restrict__ oW1, const float* __restrict__ ob1,
    const float* __restrict__ oW2, const float* __restrict__ ob2,
    const int* __restrict__ nn4, float* __restrict__ out) {
  __shared__ __align__(16) float XS[8 * EDIM];
  __shared__ __align__(16) float P[4 * 256 * 8];
  __shared__ __align__(16) float H[EDIM * 8];
  __shared__ int hist[64], meta[4], rowsl[8];
  __shared__ int wcnt2[16], wbase2[16];
  __shared__ float denom[8];
  float* const P2h = P;
  const int t = threadIdx.x;
  const int c = ((blockIdx.x & 7) * 24) + (blockIdx.x >> 3);
  const int jc = t & 127, kg = t >> 7;

  B_ROUTE(max(nn4[rr], 0))   // exited rows re-enter at origin

  { const int i = t >> 6, q = t & 63;
    const int row = rowsl[min(i, m - 1)] & 1023;
    const float4 v = *(const float4*)(state + (size_t)row * EDIM + q * 4);
    ((float4*)XS)[t] = v;
    float sq = v.x * v.x + v.y * v.y + v.z * v.z + v.w * v.w;
#pragma unroll
    for (int d = 32; d >= 1; d >>= 1) sq += __shfl_xor(sq, d);
    if (q == 0) denom[i] = sqrtf(sq) + 1e-6f;
  }
  __syncthreads();

  const float* W1n = W1 + (size_t)n * EDIM * EDIM;
  const float* W2n = W2 + (size_t)n * EDIM * EDIM;
  const int kb = kg * 64;
  { float acc[8][2] = {};
    GEMM_TILE8(W1n, jc, 128, XS, EDIM, kb, 64, acc);
    P_STORE8(P, kg, 256, jc, 128, acc);
  }
  __syncthreads();
  if (t < 256) {
    float4 lo, hi; P_REDUCE(P, t, 256, 4, b1[(size_t)n * EDIM + t], lo, hi);
    *(float4*)&H[t * 8] = make_float4(fmaxf(lo.x, 0.f), fmaxf(lo.y, 0.f),
                                      fmaxf(lo.z, 0.f), fmaxf(lo.w, 0.f));
    *(float4*)&H[t * 8 + 4] = make_float4(fmaxf(hi.x, 0.f), fmaxf(hi.y, 0.f),
                                          fmaxf(hi.z, 0.f), fmaxf(hi.w, 0.f));
  }
  __syncthreads();
  { float acc[8][2] = {};
    GEMM_TILE_H8(W2n, jc, 128, H, kb, 64, acc);
    P_STORE8(P, kg, 256, jc, 128, acc);
  }
  __syncthreads();
  if (t < 256) { // final_output = relu/denom + initial -> XS (head input)
    float4 lo, hi; P_REDUCE(P, t, 256, 4, b2[(size_t)n * EDIM + t], lo, hi);
    float sv[8] = { lo.x, lo.y, lo.z, lo.w, hi.x, hi.y, hi.z, hi.w };
#pragma unroll
    for (int i = 0; i < 8; i++) {
      const int row = rowsl[i] & 1023;
      float v = fmaxf(sv[i], 0.f) / denom[i];
      v += initial[(size_t)row * EDIM + t];
      XS[i * EDIM + t] = v;     // dup rows for i>=m harmless (guard at out)
    }
  }
  __syncthreads();

  // ---- head layer 1 (oW1) ----
  { float acc[8][2] = {};
    GEMM_TILE8(oW1, jc, 128, XS, EDIM, kb, 64, acc);
    P_STORE8(P, kg, 256, jc, 128, acc);
  }
  __syncthreads();
  if (t < 256) {
    float4 lo, hi; P_REDUCE(P, t, 256, 4, ob1[t], lo, hi);
    *(float4*)&H[t * 8] = make_float4(fmaxf(lo.x, 0.f), fmaxf(lo.y, 0.f),
                                      fmaxf(lo.z, 0.f), fmaxf(lo.w, 0.f));
    *(float4*)&H[t * 8 + 4] = make_float4(fmaxf(hi.x, 0.f), fmaxf(hi.y, 0.f),
                                          fmaxf(hi.z, 0.f), fmaxf(hi.w, 0.f));
  }
  __syncthreads();
  { // head layer 2: 32 slices of 8 (P2h aliases P; P dead after barrier)
    const int cc = t & 15, ksl = t >> 4;
    float a2[8] = {0.f,0.f,0.f,0.f,0.f,0.f,0.f,0.f};
    if (cc < 10) {
      const int k0 = ksl * 8;
#pragma unroll
      for (int k = k0; k < k0 + 8; k++) {
        const float4 hl = *(const float4*)&H[k * 8];
        const float4 hh = *(const float4*)&H[k * 8 + 4];
        const float w = oW2[k * 10 + cc];
        a2[0] = fmaf(hl.x, w, a2[0]); a2[1] = fmaf(hl.y, w, a2[1]);
        a2[2] = fmaf(hl.z, w, a2[2]); a2[3] = fmaf(hl.w, w, a2[3]);
        a2[4] = fmaf(hh.x, w, a2[4]); a2[5] = fmaf(hh.y, w, a2[5]);
        a2[6] = fmaf(hh.z, w, a2[6]); a2[7] = fmaf(hh.w, w, a2[7]);
      }
    }
    *(float4*)&P2h[(ksl * 16 + cc) * 8] = make_float4(a2[0], a2[1], a2[2], a2[3]);
    *(float4*)&P2h[(ksl * 16 + cc) * 8 + 4] = make_float4(a2[4], a2[5], a2[6], a2[7]);
  }
  __syncthreads();
  if (t < 80) {
    const int i = t / 10, cc = t % 10;
    if (i < m) {
      float s = 0.f;
#pragma unroll
      for (int w = 0; w < 32; w++) s += P2h[(w * 16 + cc) * 8 + i];
      const int row = rowsl[i] & 1023;
      out[(size_t)row * 10 + cc] = s + ob2[cc];
    }
  }
}

// ---------------- launch: 7 dispatches ----------------
extern "C" void kernel_launch(void* const* d_in, const int* in_sizes, int n_in,
                              void* d_out, int out_size, void* d_ws, size_t ws_size,
                              hipStream_t stream) {
  const float* x    = (const float*)d_in[0];
  const float* Wemb = (const float*)d_in[1];
  const float* bemb = (const float*)d_in[2];
  const float* stW1 = (const float*)d_in[3];
  const float* stb1 = (const float*)d_in[4];
  const float* stW2 = (const float*)d_in[5];
  const float* stb2 = (const float*)d_in[6];
  const float* aW1  = (const float*)d_in[7];
  const float* ab1  = (const float*)d_in[8];
  const float* aW2  = (const float*)d_in[9];
  const float* ab2  = (const float*)d_in[10];
  const float* oW1  = (const float*)d_in[11];
  const float* ob1  = (const float*)d_in[12];
  const float* oW2  = (const float*)d_in[13];
  const float* ob2  = (const float*)d_in[14];
  float* out = (float*)d_out;

  char* ws = (char*)d_ws;
  auto alloc = [&](size_t bytes) { char* p = ws; ws += (bytes + 255) & ~(size_t)255; return p; };
  float* state   = (float*)alloc((size_t)BATCH * EDIM * 4);
  float* initial = (float*)alloc((size_t)BATCH * EDIM * 4);
  int*   nn_all  = (int*)alloc(5 * BATCH * 4);

  k_embed<<<256, 512, 0, stream>>>(x, Wemb, bemb, state, initial);
  k_addr0<<<128, 512, 0, stream>>>(state, aW1, ab1, aW2, ab2, nn_all);
  for (int j = 0; j < 4; j++)
    k_block_mid<<<GRID_B, 512, 0, stream>>>(state, stW1, stb1, stW2, stb2,
                                            aW1, ab1, aW2, ab2, nn_all, j);
  k_block_final<<<GRID_B, 512, 0, stream>>>(state, stW1, stb1, stW2, stb2,
                                            initial, oW1, ob1, oW2, ob2,
                                            nn_all + 4 * BATCH, out);
}